// Round 7
// baseline (1688.077 us; speedup 1.0000x reference)
//
#include <hip/hip_runtime.h>

#define N_FUNC 200000
#define N_API  50000
#define H      64
#define NLAYERS 2
#define SCAN_CHUNK 2048
#define NBF 3125   // N_FUNC/64 exact
#define NBA 782    // ceil(N_API/64)
#define PREPB 160  // ceil(10*4096/256)
#define NSHADOW 16

__device__ __forceinline__ void fma4(float4& a, float s, float4 w) {
    a.x = fmaf(s, w.x, a.x); a.y = fmaf(s, w.y, a.y);
    a.z = fmaf(s, w.z, a.z); a.w = fmaf(s, w.w, a.w);
}
__device__ __forceinline__ void add4(float4& a, float4 v) {
    a.x += v.x; a.y += v.y; a.z += v.z; a.w += v.w;
}
__device__ __forceinline__ void scl4(float4& a, float s) {
    a.x *= s; a.y *= s; a.z *= s; a.w *= s;
}
__device__ __forceinline__ float dot4(float4 a, float4 b) {
    return fmaf(a.x, b.x, fmaf(a.y, b.y, fmaf(a.z, b.z, a.w * b.w)));
}

// ---- dot4 proj bodies: weights in ORIGINAL (64,K) row-major layout ----
__device__ __forceinline__ void projd_body128(const float* __restrict__ x,
        const float* __restrict__ W, const float* __restrict__ bias,
        float* __restrict__ hout, int i0, float4* xs)
{
    const int t = threadIdx.x;
    const int og = t & 15, ng = t >> 4;
    float acc[4][4];
    #pragma unroll
    for (int j = 0; j < 4; ++j)
        #pragma unroll
        for (int c = 0; c < 4; ++c) acc[j][c] = 0.f;
    const float4* W4 = reinterpret_cast<const float4*>(W);  // row o: W4[o*32 + k4]
    // stage ph0
    for (int idx = t; idx < 1024; idx += 256) {
        int n = idx >> 4, k4 = idx & 15;
        xs[n * 16 + (k4 ^ ((n >> 2) & 7))] =
            *reinterpret_cast<const float4*>(x + (size_t)(i0 + n) * 128 + k4 * 4);
    }
    __syncthreads();
    // T14: pre-issue ph1 loads
    float4 pr[4];
    #pragma unroll
    for (int r = 0; r < 4; ++r) {
        int idx = t + r * 256;
        int n = idx >> 4, k4 = idx & 15;
        pr[r] = *reinterpret_cast<const float4*>(x + (size_t)(i0 + n) * 128 + 64 + k4 * 4);
    }
    // gemm ph0
    #pragma unroll
    for (int ph = 0; ph < 2; ++ph) {
        if (ph) {
            __syncthreads();
            #pragma unroll
            for (int r = 0; r < 4; ++r) {
                int idx = t + r * 256;
                int n = idx >> 4, k4 = idx & 15;
                xs[n * 16 + (k4 ^ ((n >> 2) & 7))] = pr[r];
            }
            __syncthreads();
        }
        for (int k4 = 0; k4 < 16; ++k4) {
            float4 w0 = W4[(og * 4 + 0) * 32 + ph * 16 + k4];
            float4 w1 = W4[(og * 4 + 1) * 32 + ph * 16 + k4];
            float4 w2 = W4[(og * 4 + 2) * 32 + ph * 16 + k4];
            float4 w3 = W4[(og * 4 + 3) * 32 + ph * 16 + k4];
            #pragma unroll
            for (int j = 0; j < 4; ++j) {
                int n = ng * 4 + j;
                float4 xv = xs[n * 16 + (k4 ^ ((n >> 2) & 7))];
                acc[j][0] += dot4(xv, w0);
                acc[j][1] += dot4(xv, w1);
                acc[j][2] += dot4(xv, w2);
                acc[j][3] += dot4(xv, w3);
            }
        }
    }
    float4 b = reinterpret_cast<const float4*>(bias)[og];
    #pragma unroll
    for (int j = 0; j < 4; ++j) {
        int node = i0 + ng * 4 + j;
        float4 o;
        o.x = fmaxf(acc[j][0] + b.x, 0.f);
        o.y = fmaxf(acc[j][1] + b.y, 0.f);
        o.z = fmaxf(acc[j][2] + b.z, 0.f);
        o.w = fmaxf(acc[j][3] + b.w, 0.f);
        *reinterpret_cast<float4*>(hout + (size_t)node * H + og * 4) = o;
    }
}

__device__ __forceinline__ void projd_body64(const float* __restrict__ x,
        const float* __restrict__ W, const float* __restrict__ bias,
        float* __restrict__ hout, int i0, int nN, float4* xs)
{
    const int t = threadIdx.x;
    const int og = t & 15, ng = t >> 4;
    for (int idx = t; idx < 1024; idx += 256) {
        int n = idx >> 4, k4 = idx & 15;
        float4 v = make_float4(0.f, 0.f, 0.f, 0.f);
        if (i0 + n < nN)
            v = *reinterpret_cast<const float4*>(x + (size_t)(i0 + n) * 64 + k4 * 4);
        xs[n * 16 + (k4 ^ ((n >> 2) & 7))] = v;
    }
    __syncthreads();
    float acc[4][4];
    #pragma unroll
    for (int j = 0; j < 4; ++j)
        #pragma unroll
        for (int c = 0; c < 4; ++c) acc[j][c] = 0.f;
    const float4* W4 = reinterpret_cast<const float4*>(W);  // row o: W4[o*16 + k4]
    for (int k4 = 0; k4 < 16; ++k4) {
        float4 w0 = W4[(og * 4 + 0) * 16 + k4];
        float4 w1 = W4[(og * 4 + 1) * 16 + k4];
        float4 w2 = W4[(og * 4 + 2) * 16 + k4];
        float4 w3 = W4[(og * 4 + 3) * 16 + k4];
        #pragma unroll
        for (int j = 0; j < 4; ++j) {
            int n = ng * 4 + j;
            float4 xv = xs[n * 16 + (k4 ^ ((n >> 2) & 7))];
            acc[j][0] += dot4(xv, w0);
            acc[j][1] += dot4(xv, w1);
            acc[j][2] += dot4(xv, w2);
            acc[j][3] += dot4(xv, w3);
        }
    }
    float4 b = reinterpret_cast<const float4*>(bias)[og];
    #pragma unroll
    for (int j = 0; j < 4; ++j) {
        int node = i0 + ng * 4 + j;
        if (node < nN) {
            float4 o;
            o.x = fmaxf(acc[j][0] + b.x, 0.f);
            o.y = fmaxf(acc[j][1] + b.y, 0.f);
            o.z = fmaxf(acc[j][2] + b.z, 0.f);
            o.w = fmaxf(acc[j][3] + b.w, 0.f);
            *reinterpret_cast<float4*>(hout + (size_t)node * H + og * 4) = o;
        }
    }
}

// ---- K1: layer-weight prep + edge histogram + BOTH projections in one launch ----
__global__ __launch_bounds__(256, 6) void prep_count_proj(
        const float* __restrict__ Wl_calls, const float* __restrict__ Wr_calls,
        const float* __restrict__ Wl_uses,  const float* __restrict__ Wr_uses,
        const float* __restrict__ Wl_usedby,const float* __restrict__ Wr_usedby,
        float* __restrict__ prep,
        const int* __restrict__ dC, const int* __restrict__ dU, const int* __restrict__ dA,
        int* __restrict__ cC, int* __restrict__ cU, int* __restrict__ cA, int E, int countB,
        const float* __restrict__ xf, const float* __restrict__ wf,
        const float* __restrict__ bf, float* __restrict__ hf,
        const float* __restrict__ xa, const float* __restrict__ wa,
        const float* __restrict__ ba, float* __restrict__ ha)
{
    __shared__ __align__(16) float4 xs[64 * 16];
    int b = blockIdx.x;
    if (b < PREPB) {
        int idx = b * 256 + threadIdx.x;   // < 40960
        int m = idx >> 12, w = idx & 4095;
        int k = w >> 6, o = w & 63;
        int l = m / 5, which = m - 5 * l;
        const float* A; const float* B = nullptr;
        if (which == 0)      { A = Wr_calls  + l * 4096; B = Wr_usedby + l * 4096; }
        else if (which == 1)   A = Wl_calls  + l * 4096;
        else if (which == 2)   A = Wl_usedby + l * 4096;
        else if (which == 3)   A = Wl_uses   + l * 4096;
        else                   A = Wr_uses   + l * 4096;
        float v = A[o * 64 + k];
        if (B) v += B[o * 64 + k];
        prep[idx] = v;
    } else if (b < PREPB + countB) {
        int i = (b - PREPB) * 256 + threadIdx.x;
        if (i >= 3 * E) return;
        int rel = i / E, e = i - rel * E;
        if (rel == 0)      atomicAdd(&cC[dC[e]], 1);
        else if (rel == 1) atomicAdd(&cU[dU[e]], 1);
        else               atomicAdd(&cA[dA[e]], 1);
    } else {
        int b2 = b - PREPB - countB;
        if (b2 < NBF) projd_body128(xf, wf, bf, hf, b2 * 64, xs);
        else          projd_body64(xa, wa, ba, ha, (b2 - NBF) * 64, N_API, xs);
    }
}

__global__ __launch_bounds__(256) void block_sums_all(
        const int* __restrict__ cC, const int* __restrict__ cU, const int* __restrict__ cA,
        int* __restrict__ pC, int* __restrict__ pU, int* __restrict__ pA,
        int nF, int nA, int nbF)
{
    __shared__ int sd[256];
    int b = blockIdx.x, t = threadIdx.x;
    const int* cnt; int* part; int n, lb;
    if (b < nbF)            { cnt = cC; part = pC; n = nF; lb = b; }
    else if (b < 2 * nbF)   { cnt = cU; part = pU; n = nF; lb = b - nbF; }
    else                    { cnt = cA; part = pA; n = nA; lb = b - 2 * nbF; }
    int base = lb * SCAN_CHUNK;
    int s = 0;
    for (int i = t; i < SCAN_CHUNK; i += 256) {
        int idx = base + i;
        s += (idx < n) ? cnt[idx] : 0;
    }
    sd[t] = s; __syncthreads();
    for (int st = 128; st > 0; st >>= 1) {
        if (t < st) sd[t] += sd[t + st];
        __syncthreads();
    }
    if (t == 0) part[lb] = sd[0];
}

__global__ __launch_bounds__(192) void scan_small_all(int* pC, int* pU, int* pA, int nbF, int nbA)
{
    int w = threadIdx.x >> 6, lane = threadIdx.x & 63;
    int* p = (w == 0) ? pC : (w == 1) ? pU : pA;
    int nb = (w == 2) ? nbA : nbF;
    int o0 = (lane < nb) ? p[lane] : 0;
    int o1 = (64 + lane < nb) ? p[64 + lane] : 0;
    int v0 = o0, v1 = o1;
    for (int off = 1; off < 64; off <<= 1) {
        int x0 = __shfl_up(v0, off);
        int x1 = __shfl_up(v1, off);
        if (lane >= off) { v0 += x0; v1 += x1; }
    }
    int tot0 = __shfl(v0, 63);
    if (lane < nb) p[lane] = v0 - o0;
    if (64 + lane < nb) p[64 + lane] = tot0 + v1 - o1;
}

__global__ __launch_bounds__(256) void write_rowptr_all(
        const int* __restrict__ cC, const int* __restrict__ cU, const int* __restrict__ cA,
        const int* __restrict__ pC, const int* __restrict__ pU, const int* __restrict__ pA,
        int* __restrict__ rpC, int* __restrict__ rpU, int* __restrict__ rpA,
        int* __restrict__ nxC, int* __restrict__ nxU, int* __restrict__ nxA,
        int nF, int nA, int nbF, int E)
{
    __shared__ int sc[256];
    int b = blockIdx.x, t = threadIdx.x;
    const int* cnt; const int* part; int* rp; int* nx; int n, lb;
    if (b < nbF)            { cnt = cC; part = pC; rp = rpC; nx = nxC; n = nF; lb = b; }
    else if (b < 2 * nbF)   { cnt = cU; part = pU; rp = rpU; nx = nxU; n = nF; lb = b - nbF; }
    else                    { cnt = cA; part = pA; rp = rpA; nx = nxA; n = nA; lb = b - 2 * nbF; }
    int base = lb * SCAN_CHUNK;
    int loc[8]; int s = 0;
    #pragma unroll
    for (int i = 0; i < 8; ++i) {
        int idx = base + t * 8 + i;
        int v = (idx < n) ? cnt[idx] : 0;
        loc[i] = s; s += v;
    }
    sc[t] = s; __syncthreads();
    for (int st = 1; st < 256; st <<= 1) {
        int v = (t >= st) ? sc[t - st] : 0;
        __syncthreads();
        sc[t] += v;
        __syncthreads();
    }
    int off = part[lb] + (t > 0 ? sc[t - 1] : 0);
    #pragma unroll
    for (int i = 0; i < 8; ++i) {
        int idx = base + t * 8 + i;
        if (idx < n) { int v = off + loc[i]; rp[idx] = v; nx[idx] = v; }
    }
    if (lb == 0 && t == 0) rp[n] = E;
}

// ---- K5: CSR fill (standalone) ----
__global__ __launch_bounds__(256, 8) void fill_all(
        const int* __restrict__ sC, const int* __restrict__ dC,
        const int* __restrict__ sU, const int* __restrict__ dU,
        const int* __restrict__ sA, const int* __restrict__ dA,
        int* __restrict__ nxC, int* __restrict__ nxU, int* __restrict__ nxA,
        int* __restrict__ colC, int* __restrict__ colU, int* __restrict__ colA, int E)
{
    int i = blockIdx.x * 256 + threadIdx.x;
    if (i >= 3 * E) return;
    int rel = i / E, e = i - rel * E;
    if (rel == 0)      { int pos = atomicAdd(&nxC[dC[e]], 1); colC[pos] = sC[e]; }
    else if (rel == 1) { int pos = atomicAdd(&nxU[dU[e]], 1); colU[pos] = sU[e]; }
    else               { int pos = atomicAdd(&nxA[dA[e]], 1); colA[pos] = sA[e]; }
}

// ---- GEMM-accumulate over 64x64 LDS tile (XOR-swizzled), transposed weights ----
__device__ __forceinline__ void gemm_acc(const float4* X, const float4* __restrict__ wt4,
        int og, int ng, float4 acc[4])
{
    for (int k4 = 0; k4 < 16; ++k4) {
        float4 w0 = wt4[(4 * k4 + 0) * 16 + og];
        float4 w1 = wt4[(4 * k4 + 1) * 16 + og];
        float4 w2 = wt4[(4 * k4 + 2) * 16 + og];
        float4 w3 = wt4[(4 * k4 + 3) * 16 + og];
        #pragma unroll
        for (int j = 0; j < 4; ++j) {
            int n = ng * 4 + j;
            float4 xv = X[n * 16 + (k4 ^ ((n >> 2) & 7))];
            fma4(acc[j], xv.x, w0); fma4(acc[j], xv.y, w1);
            fma4(acc[j], xv.z, w2); fma4(acc[j], xv.w, w3);
        }
    }
}

// ---- 8-deep interleaved CSR gather ----
__device__ __forceinline__ void gather8(const float* __restrict__ src,
        const int* __restrict__ col, int j[4], const int e[4], int L, float4 a[4])
{
    while (j[0] < e[0] || j[1] < e[1] || j[2] < e[2] || j[3] < e[3]) {
        float4 v[8]; bool act[8];
        #pragma unroll
        for (int p = 0; p < 4; ++p) {
            int jj = j[p];
            act[2 * p]     = jj < e[p];
            act[2 * p + 1] = jj + 1 < e[p];
            if (act[2 * p]) {
                int s = col[jj];
                v[2 * p] = *reinterpret_cast<const float4*>(src + (size_t)s * H + L * 4);
            }
            if (act[2 * p + 1]) {
                int s = col[jj + 1];
                v[2 * p + 1] = *reinterpret_cast<const float4*>(src + (size_t)s * H + L * 4);
            }
            j[p] = jj + 2;
        }
        #pragma unroll
        for (int q = 0; q < 8; ++q) if (act[q]) add4(a[q >> 1], v[q]);
    }
}

// ---- fused layer with T14 pre-issue + optional fused mean-pool (shadowed atomics) ----
__global__ __launch_bounds__(256, 4) void layer_both(
        const float* __restrict__ hf_old, const float* __restrict__ ha_old,
        float* __restrict__ hf_new, float* __restrict__ ha_new,
        const int* __restrict__ rpC, const int* __restrict__ colC,
        const int* __restrict__ rpU, const int* __restrict__ colU,
        const int* __restrict__ rpA, const int* __restrict__ colA,
        const float* __restrict__ wtr, const float* __restrict__ wtlc,
        const float* __restrict__ wtlu,
        const float* __restrict__ wtruse, const float* __restrict__ wtluse,
        const float* __restrict__ bias_c, const float* __restrict__ bias_u,
        const float* __restrict__ bias_a,
        float* __restrict__ psh)   // nullptr for layer 0; else [NSHADOW][128] shadow sums
{
    __shared__ __align__(16) float4 X[64 * 16];
    const int b = blockIdx.x;
    const int t = threadIdx.x;
    const int L = t & 15, g = t >> 4;
    const int og = t & 15, ng = t >> 4;
    const float4 z4 = make_float4(0.f, 0.f, 0.f, 0.f);

    float4 acc[4];
    #pragma unroll
    for (int j = 0; j < 4; ++j) acc[j] = z4;
    float4 o4[4];

    if (b < NBF) {
        const int i0 = b * 64;
        // ---- P1: calls gather (fully exposed) ----
        {
            int j1[4], e1[4], d1[4]; float4 a1[4];
            #pragma unroll
            for (int p = 0; p < 4; ++p) {
                int node = i0 + p * 16 + g;
                j1[p] = rpC[node]; e1[p] = rpC[node + 1]; d1[p] = e1[p] - j1[p];
                a1[p] = z4;
            }
            gather8(hf_old, colC, j1, e1, L, a1);
            #pragma unroll
            for (int p = 0; p < 4; ++p) {
                int n = p * 16 + g;
                scl4(a1[p], 1.0f / (float)max(d1[p], 1));
                X[n * 16 + (L ^ ((n >> 2) & 7))] = a1[p];
            }
        }
        __syncthreads();
        // ---- P2 init + pre-issue round 1 (T14) ----
        int j2[4], e2[4], d2[4]; float4 a2[4];
        float4 v2[8]; bool act2[8];
        #pragma unroll
        for (int p = 0; p < 4; ++p) {
            int node = i0 + p * 16 + g;
            j2[p] = rpU[node]; e2[p] = rpU[node + 1]; d2[p] = e2[p] - j2[p];
            a2[p] = z4;
            int jj = j2[p];
            act2[2 * p]     = jj < e2[p];
            act2[2 * p + 1] = jj + 1 < e2[p];
            if (act2[2 * p])
                v2[2 * p] = *reinterpret_cast<const float4*>(ha_old + (size_t)colU[jj] * H + L * 4);
            if (act2[2 * p + 1])
                v2[2 * p + 1] = *reinterpret_cast<const float4*>(ha_old + (size_t)colU[jj + 1] * H + L * 4);
            j2[p] = jj + 2;
        }
        gemm_acc(X, reinterpret_cast<const float4*>(wtlc), og, ng, acc);   // gemm1 hides v2
        __syncthreads();
        // ---- P2 finish ----
        #pragma unroll
        for (int q = 0; q < 8; ++q) if (act2[q]) add4(a2[q >> 1], v2[q]);
        gather8(ha_old, colU, j2, e2, L, a2);
        #pragma unroll
        for (int p = 0; p < 4; ++p) {
            int n = p * 16 + g;
            scl4(a2[p], 1.0f / (float)max(d2[p], 1));
            X[n * 16 + (L ^ ((n >> 2) & 7))] = a2[p];
        }
        __syncthreads();
        // ---- P3 pre-issue own rows (T14) ----
        float4 ow[4];
        #pragma unroll
        for (int r = 0; r < 4; ++r) {
            int idx = t + r * 256;
            int n = idx >> 4, k4 = idx & 15;
            ow[r] = *reinterpret_cast<const float4*>(hf_old + (size_t)(i0 + n) * H + k4 * 4);
        }
        gemm_acc(X, reinterpret_cast<const float4*>(wtlu), og, ng, acc);   // gemm2 hides ow
        __syncthreads();
        #pragma unroll
        for (int r = 0; r < 4; ++r) {
            int idx = t + r * 256;
            int n = idx >> 4, k4 = idx & 15;
            X[n * 16 + (k4 ^ ((n >> 2) & 7))] = ow[r];
        }
        __syncthreads();
        gemm_acc(X, reinterpret_cast<const float4*>(wtr), og, ng, acc);    // gemm3
        // ---- epilogue ----
        float4 ba = reinterpret_cast<const float4*>(bias_c)[og];
        float4 bb = reinterpret_cast<const float4*>(bias_u)[og];
        float4 bv = make_float4(ba.x + bb.x, ba.y + bb.y, ba.z + bb.z, ba.w + bb.w);
        #pragma unroll
        for (int j = 0; j < 4; ++j) {
            int node = i0 + ng * 4 + j;
            float4 o;
            o.x = fmaxf(acc[j].x + bv.x, 0.f);
            o.y = fmaxf(acc[j].y + bv.y, 0.f);
            o.z = fmaxf(acc[j].z + bv.z, 0.f);
            o.w = fmaxf(acc[j].w + bv.w, 0.f);
            o4[j] = o;
            *reinterpret_cast<float4*>(hf_new + (size_t)node * H + og * 4) = o;
        }
        if (psh) {
            float4 s = z4;
            #pragma unroll
            for (int j = 0; j < 4; ++j) add4(s, o4[j]);
            __syncthreads();
            X[ng * 16 + og] = s;
            __syncthreads();
            if (ng == 0) {
                float4 tot = z4;
                #pragma unroll
                for (int q = 0; q < 16; ++q) add4(tot, X[q * 16 + og]);
                float* dst = psh + (size_t)(b & (NSHADOW - 1)) * 128 + og * 4;
                atomicAdd(dst + 0, tot.x); atomicAdd(dst + 1, tot.y);
                atomicAdd(dst + 2, tot.z); atomicAdd(dst + 3, tot.w);
            }
        }
    } else {
        const int i0 = (b - NBF) * 64;
        // ---- P1: uses gather ----
        {
            int j1[4], e1[4], d1[4]; float4 a1[4];
            #pragma unroll
            for (int p = 0; p < 4; ++p) {
                int node = i0 + p * 16 + g;
                if (node < N_API) { j1[p] = rpA[node]; e1[p] = rpA[node + 1]; }
                else { j1[p] = 0; e1[p] = 0; }
                d1[p] = e1[p] - j1[p];
                a1[p] = z4;
            }
            gather8(hf_old, colA, j1, e1, L, a1);
            #pragma unroll
            for (int p = 0; p < 4; ++p) {
                int n = p * 16 + g;
                scl4(a1[p], 1.0f / (float)max(d1[p], 1));
                X[n * 16 + (L ^ ((n >> 2) & 7))] = a1[p];
            }
        }
        __syncthreads();
        // ---- pre-issue own rows ----
        float4 ow[4];
        #pragma unroll
        for (int r = 0; r < 4; ++r) {
            int idx = t + r * 256;
            int n = idx >> 4, k4 = idx & 15;
            int node = i0 + n;
            ow[r] = z4;
            if (node < N_API)
                ow[r] = *reinterpret_cast<const float4*>(ha_old + (size_t)node * H + k4 * 4);
        }
        gemm_acc(X, reinterpret_cast<const float4*>(wtluse), og, ng, acc);
        __syncthreads();
        #pragma unroll
        for (int r = 0; r < 4; ++r) {
            int idx = t + r * 256;
            int n = idx >> 4, k4 = idx & 15;
            X[n * 16 + (k4 ^ ((n >> 2) & 7))] = ow[r];
        }
        __syncthreads();
        gemm_acc(X, reinterpret_cast<const float4*>(wtruse), og, ng, acc);
        float4 bv = reinterpret_cast<const float4*>(bias_a)[og];
        #pragma unroll
        for (int j = 0; j < 4; ++j) o4[j] = z4;
        #pragma unroll
        for (int j = 0; j < 4; ++j) {
            int node = i0 + ng * 4 + j;
            if (node < N_API) {
                float4 o;
                o.x = fmaxf(acc[j].x + bv.x, 0.f);
                o.y = fmaxf(acc[j].y + bv.y, 0.f);
                o.z = fmaxf(acc[j].z + bv.z, 0.f);
                o.w = fmaxf(acc[j].w + bv.w, 0.f);
                o4[j] = o;
                *reinterpret_cast<float4*>(ha_new + (size_t)node * H + og * 4) = o;
            }
        }
        if (psh) {
            float4 s = z4;
            #pragma unroll
            for (int j = 0; j < 4; ++j) add4(s, o4[j]);
            __syncthreads();
            X[ng * 16 + og] = s;
            __syncthreads();
            if (ng == 0) {
                float4 tot = z4;
                #pragma unroll
                for (int q = 0; q < 16; ++q) add4(tot, X[q * 16 + og]);
                float* dst = psh + (size_t)(b & (NSHADOW - 1)) * 128 + 64 + og * 4;
                atomicAdd(dst + 0, tot.x); atomicAdd(dst + 1, tot.y);
                atomicAdd(dst + 2, tot.z); atomicAdd(dst + 3, tot.w);
            }
        }
    }
}

__global__ __launch_bounds__(128) void classifier_kernel(const float* __restrict__ shadows,
        const float* __restrict__ Wc1, const float* __restrict__ bc1,
        const float* __restrict__ Wc2, const float* __restrict__ bc2,
        float* __restrict__ out)
{
    __shared__ float ps[128];
    __shared__ float z1[64];
    int t = threadIdx.x;
    float s = 0.f;
    for (int q = 0; q < NSHADOW; ++q) s += shadows[q * 128 + t];
    ps[t] = s * (t < 64 ? (1.0f / N_FUNC) : (1.0f / N_API));
    __syncthreads();
    if (t < 64) {
        float a = bc1[t];
        for (int k = 0; k < 128; ++k) a = fmaf(ps[k], Wc1[t * 128 + k], a);
        z1[t] = fmaxf(a, 0.f);
    }
    __syncthreads();
    if (t < 2) {
        float a = bc2[t];
        for (int j = 0; j < 64; ++j) a = fmaf(z1[j], Wc2[t * 64 + j], a);
        out[t] = a;
    }
}

extern "C" void kernel_launch(void* const* d_in, const int* in_sizes, int n_in,
                              void* d_out, int out_size, void* d_ws, size_t ws_size,
                              hipStream_t stream)
{
    const float* x_func    = (const float*)d_in[0];
    const float* x_api     = (const float*)d_in[1];
    const float* w_in_func = (const float*)d_in[2];
    const float* b_in_func = (const float*)d_in[3];
    const float* w_in_api  = (const float*)d_in[4];
    const float* b_in_api  = (const float*)d_in[5];
    const float* Wl_calls  = (const float*)d_in[6];
    const float* bl_calls  = (const float*)d_in[7];
    const float* Wr_calls  = (const float*)d_in[8];
    const float* Wl_uses   = (const float*)d_in[9];
    const float* bl_uses   = (const float*)d_in[10];
    const float* Wr_uses   = (const float*)d_in[11];
    const float* Wl_usedby = (const float*)d_in[12];
    const float* bl_usedby = (const float*)d_in[13];
    const float* Wr_usedby = (const float*)d_in[14];
    const float* Wc1       = (const float*)d_in[15];
    const float* bc1       = (const float*)d_in[16];
    const float* Wc2       = (const float*)d_in[17];
    const float* bc2       = (const float*)d_in[18];
    const int*   ei_calls  = (const int*)d_in[19];
    const int*   ei_uses   = (const int*)d_in[20];
    const int*   ei_usedby = (const int*)d_in[21];
    const int E = in_sizes[19] / 2;

    float* ws = (float*)d_ws;
    size_t off = 0;
    float* hf0 = ws + off; off += (size_t)N_FUNC * H;
    float* hf1 = ws + off; off += (size_t)N_FUNC * H;
    float* ha0 = ws + off; off += (size_t)N_API * H;
    float* ha1 = ws + off; off += (size_t)N_API * H;
    float* prep = ws + off; off += 10 * 4096;
    int* cntC = (int*)(ws + off); off += N_FUNC;   // cnt block + shadows contiguous for 1 memset
    int* cntU = (int*)(ws + off); off += N_FUNC;
    int* cntA = (int*)(ws + off); off += N_API;
    float* shadows = ws + off; off += NSHADOW * 128;
    int* rpC = (int*)(ws + off); off += N_FUNC + 1;
    int* rpU = (int*)(ws + off); off += N_FUNC + 1;
    int* rpA = (int*)(ws + off); off += N_API + 1;
    int* nxC = (int*)(ws + off); off += N_FUNC + 1;
    int* nxU = (int*)(ws + off); off += N_FUNC + 1;
    int* nxA = (int*)(ws + off); off += N_API + 1;
    int* colC = (int*)(ws + off); off += E;
    int* colU = (int*)(ws + off); off += E;
    int* colA = (int*)(ws + off); off += E;
    int* partC = (int*)(ws + off); off += 128;
    int* partU = (int*)(ws + off); off += 128;
    int* partA = (int*)(ws + off); off += 128;

    const int nbF = (N_FUNC + SCAN_CHUNK - 1) / SCAN_CHUNK;  // 98
    const int nbA = (N_API + SCAN_CHUNK - 1) / SCAN_CHUNK;   // 25
    const int countB = (3 * E + 255) / 256;

    hipMemsetAsync(cntC, 0, (size_t)(2 * N_FUNC + N_API + NSHADOW * 128) * sizeof(float), stream);

    prep_count_proj<<<PREPB + countB + NBF + NBA, 256, 0, stream>>>(
            Wl_calls, Wr_calls, Wl_uses, Wr_uses, Wl_usedby, Wr_usedby, prep,
            ei_calls + E, ei_usedby + E, ei_uses + E, cntC, cntU, cntA, E, countB,
            x_func, w_in_func, b_in_func, hf0,
            x_api, w_in_api, b_in_api, ha0);

    float* wt_r[NLAYERS], *wt_lc[NLAYERS], *wt_lu[NLAYERS], *wt_luse[NLAYERS], *wt_ruse[NLAYERS];
    for (int l = 0; l < NLAYERS; ++l) {
        wt_r[l]    = prep + (l * 5 + 0) * 4096;
        wt_lc[l]   = prep + (l * 5 + 1) * 4096;
        wt_lu[l]   = prep + (l * 5 + 2) * 4096;
        wt_luse[l] = prep + (l * 5 + 3) * 4096;
        wt_ruse[l] = prep + (l * 5 + 4) * 4096;
    }

    block_sums_all<<<2 * nbF + nbA, 256, 0, stream>>>(
            cntC, cntU, cntA, partC, partU, partA, N_FUNC, N_API, nbF);
    scan_small_all<<<1, 192, 0, stream>>>(partC, partU, partA, nbF, nbA);
    write_rowptr_all<<<2 * nbF + nbA, 256, 0, stream>>>(
            cntC, cntU, cntA, partC, partU, partA,
            rpC, rpU, rpA, nxC, nxU, nxA, N_FUNC, N_API, nbF, E);
    fill_all<<<countB, 256, 0, stream>>>(
            ei_calls, ei_calls + E, ei_usedby, ei_usedby + E, ei_uses, ei_uses + E,
            nxC, nxU, nxA, colC, colU, colA, E);

    float* hf[2] = { hf0, hf1 };
    float* ha[2] = { ha0, ha1 };
    for (int l = 0; l < NLAYERS; ++l) {
        int cur = l & 1, nxt = cur ^ 1;
        layer_both<<<NBF + NBA, 256, 0, stream>>>(
                hf[cur], ha[cur], hf[nxt], ha[nxt],
                rpC, colC, rpU, colU, rpA, colA,
                wt_r[l], wt_lc[l], wt_lu[l], wt_ruse[l], wt_luse[l],
                bl_calls + l * 64, bl_usedby + l * 64, bl_uses + l * 64,
                (l == NLAYERS - 1) ? shadows : nullptr);
    }

    classifier_kernel<<<1, 128, 0, stream>>>(shadows, Wc1, bc1, Wc2, bc2, (float*)d_out);
}

// Round 8
// 557.693 us; speedup vs baseline: 3.0269x; 3.0269x over previous
//
#include <hip/hip_runtime.h>

#define N_FUNC 200000
#define N_API  50000
#define H      64
#define NLAYERS 2
#define SCAN_CHUNK 2048
#define NBF 3125   // N_FUNC/64 exact
#define NBA 782    // ceil(N_API/64)
#define PREP_BLOCKS 208  // ceil(53248/256)
#define NSHADOW 64

__device__ __forceinline__ void fma4(float4& a, float s, float4 w) {
    a.x = fmaf(s, w.x, a.x); a.y = fmaf(s, w.y, a.y);
    a.z = fmaf(s, w.z, a.z); a.w = fmaf(s, w.w, a.w);
}
__device__ __forceinline__ void add4(float4& a, float4 v) {
    a.x += v.x; a.y += v.y; a.z += v.z; a.w += v.w;
}
__device__ __forceinline__ void scl4(float4& a, float s) {
    a.x *= s; a.y *= s; a.z *= s; a.w *= s;
}

// ---- K1: weight prep (208 blocks) + edge histogram (rest) in one launch ----
__global__ __launch_bounds__(256) void prep_and_count(
        const float* __restrict__ w_in_func, const float* __restrict__ w_in_api,
        const float* __restrict__ Wl_calls, const float* __restrict__ Wr_calls,
        const float* __restrict__ Wl_uses,  const float* __restrict__ Wr_uses,
        const float* __restrict__ Wl_usedby,const float* __restrict__ Wr_usedby,
        float* __restrict__ out,
        const int* __restrict__ dC, const int* __restrict__ dU, const int* __restrict__ dA,
        int* __restrict__ cC, int* __restrict__ cU, int* __restrict__ cA, int E)
{
    int b = blockIdx.x;
    if (b < PREP_BLOCKS) {
        int idx = b * 256 + threadIdx.x;
        if (idx < 8192) {
            int k = idx >> 6, o = idx & 63;
            out[idx] = w_in_func[o * 128 + k];
        } else if (idx < 12288) {
            int r = idx - 8192; int k = r >> 6, o = r & 63;
            out[idx] = w_in_api[o * 64 + k];
        } else if (idx < 12288 + 10 * 4096) {
            int r = idx - 12288;
            int m = r >> 12, w = r & 4095;
            int k = w >> 6, o = w & 63;
            int l = m / 5, which = m - 5 * l;
            const float* A; const float* B = nullptr;
            if (which == 0)      { A = Wr_calls  + l * 4096; B = Wr_usedby + l * 4096; }
            else if (which == 1)   A = Wl_calls  + l * 4096;
            else if (which == 2)   A = Wl_usedby + l * 4096;
            else if (which == 3)   A = Wl_uses   + l * 4096;
            else                   A = Wr_uses   + l * 4096;
            float v = A[o * 64 + k];
            if (B) v += B[o * 64 + k];
            out[idx] = v;
        }
    } else {
        int i = (b - PREP_BLOCKS) * 256 + threadIdx.x;
        if (i >= 3 * E) return;
        int rel = i / E, e = i - rel * E;
        if (rel == 0)      atomicAdd(&cC[dC[e]], 1);
        else if (rel == 1) atomicAdd(&cU[dU[e]], 1);
        else               atomicAdd(&cA[dA[e]], 1);
    }
}

__global__ __launch_bounds__(256) void block_sums_all(
        const int* __restrict__ cC, const int* __restrict__ cU, const int* __restrict__ cA,
        int* __restrict__ pC, int* __restrict__ pU, int* __restrict__ pA,
        int nF, int nA, int nbF)
{
    __shared__ int sd[256];
    int b = blockIdx.x, t = threadIdx.x;
    const int* cnt; int* part; int n, lb;
    if (b < nbF)            { cnt = cC; part = pC; n = nF; lb = b; }
    else if (b < 2 * nbF)   { cnt = cU; part = pU; n = nF; lb = b - nbF; }
    else                    { cnt = cA; part = pA; n = nA; lb = b - 2 * nbF; }
    int base = lb * SCAN_CHUNK;
    int s = 0;
    for (int i = t; i < SCAN_CHUNK; i += 256) {
        int idx = base + i;
        s += (idx < n) ? cnt[idx] : 0;
    }
    sd[t] = s; __syncthreads();
    for (int st = 128; st > 0; st >>= 1) {
        if (t < st) sd[t] += sd[t + st];
        __syncthreads();
    }
    if (t == 0) part[lb] = sd[0];
}

__global__ __launch_bounds__(192) void scan_small_all(int* pC, int* pU, int* pA, int nbF, int nbA)
{
    int w = threadIdx.x >> 6, lane = threadIdx.x & 63;
    int* p = (w == 0) ? pC : (w == 1) ? pU : pA;
    int nb = (w == 2) ? nbA : nbF;
    int o0 = (lane < nb) ? p[lane] : 0;
    int o1 = (64 + lane < nb) ? p[64 + lane] : 0;
    int v0 = o0, v1 = o1;
    for (int off = 1; off < 64; off <<= 1) {
        int x0 = __shfl_up(v0, off);
        int x1 = __shfl_up(v1, off);
        if (lane >= off) { v0 += x0; v1 += x1; }
    }
    int tot0 = __shfl(v0, 63);
    if (lane < nb) p[lane] = v0 - o0;
    if (64 + lane < nb) p[64 + lane] = tot0 + v1 - o1;
}

__global__ __launch_bounds__(256) void write_rowptr_all(
        const int* __restrict__ cC, const int* __restrict__ cU, const int* __restrict__ cA,
        const int* __restrict__ pC, const int* __restrict__ pU, const int* __restrict__ pA,
        int* __restrict__ rpC, int* __restrict__ rpU, int* __restrict__ rpA,
        int* __restrict__ nxC, int* __restrict__ nxU, int* __restrict__ nxA,
        int nF, int nA, int nbF, int E)
{
    __shared__ int sc[256];
    int b = blockIdx.x, t = threadIdx.x;
    const int* cnt; const int* part; int* rp; int* nx; int n, lb;
    if (b < nbF)            { cnt = cC; part = pC; rp = rpC; nx = nxC; n = nF; lb = b; }
    else if (b < 2 * nbF)   { cnt = cU; part = pU; rp = rpU; nx = nxU; n = nF; lb = b - nbF; }
    else                    { cnt = cA; part = pA; rp = rpA; nx = nxA; n = nA; lb = b - 2 * nbF; }
    int base = lb * SCAN_CHUNK;
    int loc[8]; int s = 0;
    #pragma unroll
    for (int i = 0; i < 8; ++i) {
        int idx = base + t * 8 + i;
        int v = (idx < n) ? cnt[idx] : 0;
        loc[i] = s; s += v;
    }
    sc[t] = s; __syncthreads();
    for (int st = 1; st < 256; st <<= 1) {
        int v = (t >= st) ? sc[t - st] : 0;
        __syncthreads();
        sc[t] += v;
        __syncthreads();
    }
    int off = part[lb] + (t > 0 ? sc[t - 1] : 0);
    #pragma unroll
    for (int i = 0; i < 8; ++i) {
        int idx = base + t * 8 + i;
        if (idx < n) { int v = off + loc[i]; rp[idx] = v; nx[idx] = v; }
    }
    if (lb == 0 && t == 0) rp[n] = E;
}

// ---- shared GEMM-accumulate over a 64x64 LDS tile (XOR-swizzled) ----
__device__ __forceinline__ void gemm_acc(const float4* X, const float4* __restrict__ wt4,
        int og, int ng, float4 acc[4])
{
    for (int k4 = 0; k4 < 16; ++k4) {
        float4 w0 = wt4[(4 * k4 + 0) * 16 + og];
        float4 w1 = wt4[(4 * k4 + 1) * 16 + og];
        float4 w2 = wt4[(4 * k4 + 2) * 16 + og];
        float4 w3 = wt4[(4 * k4 + 3) * 16 + og];
        #pragma unroll
        for (int j = 0; j < 4; ++j) {
            int n = ng * 4 + j;
            float4 xv = X[n * 16 + (k4 ^ ((n >> 2) & 7))];
            fma4(acc[j], xv.x, w0); fma4(acc[j], xv.y, w1);
            fma4(acc[j], xv.z, w2); fma4(acc[j], xv.w, w3);
        }
    }
}

// ---- proj bodies (16KB LDS) ----
__device__ __forceinline__ void proj_body128(const float* __restrict__ x,
        const float* __restrict__ wt, const float* __restrict__ bias,
        float* __restrict__ hout, int i0, float4* smem)
{
    const int t = threadIdx.x;
    const int og = t & 15, ng = t >> 4;
    float4 acc[4];
    #pragma unroll
    for (int j = 0; j < 4; ++j) acc[j] = make_float4(0.f, 0.f, 0.f, 0.f);
    const float4* w4 = reinterpret_cast<const float4*>(wt);
    #pragma unroll
    for (int ph = 0; ph < 2; ++ph) {
        if (ph) __syncthreads();
        for (int idx = t; idx < 1024; idx += 256) {
            int n = idx >> 4, k4 = idx & 15;
            smem[n * 16 + (k4 ^ ((n >> 2) & 7))] =
                *reinterpret_cast<const float4*>(x + (size_t)(i0 + n) * 128 + ph * 64 + k4 * 4);
        }
        __syncthreads();
        gemm_acc(smem, w4 + ph * 1024, og, ng, acc);
    }
    float4 b = reinterpret_cast<const float4*>(bias)[og];
    #pragma unroll
    for (int j = 0; j < 4; ++j) {
        int node = i0 + ng * 4 + j;
        float4 o;
        o.x = fmaxf(acc[j].x + b.x, 0.f);
        o.y = fmaxf(acc[j].y + b.y, 0.f);
        o.z = fmaxf(acc[j].z + b.z, 0.f);
        o.w = fmaxf(acc[j].w + b.w, 0.f);
        *reinterpret_cast<float4*>(hout + (size_t)node * H + og * 4) = o;
    }
}

__device__ __forceinline__ void proj_body64(const float* __restrict__ x,
        const float* __restrict__ wt, const float* __restrict__ bias,
        float* __restrict__ hout, int i0, int nN, float4* smem)
{
    const int t = threadIdx.x;
    for (int idx = t; idx < 1024; idx += 256) {
        int n = idx >> 4, k4 = idx & 15;
        float4 v = make_float4(0.f, 0.f, 0.f, 0.f);
        if (i0 + n < nN)
            v = *reinterpret_cast<const float4*>(x + (size_t)(i0 + n) * 64 + k4 * 4);
        smem[n * 16 + (k4 ^ ((n >> 2) & 7))] = v;
    }
    __syncthreads();
    const int og = t & 15, ng = t >> 4;
    float4 acc[4];
    #pragma unroll
    for (int j = 0; j < 4; ++j) acc[j] = make_float4(0.f, 0.f, 0.f, 0.f);
    gemm_acc(smem, reinterpret_cast<const float4*>(wt), og, ng, acc);
    float4 b = reinterpret_cast<const float4*>(bias)[og];
    #pragma unroll
    for (int j = 0; j < 4; ++j) {
        int node = i0 + ng * 4 + j;
        if (node < nN) {
            float4 o;
            o.x = fmaxf(acc[j].x + b.x, 0.f);
            o.y = fmaxf(acc[j].y + b.y, 0.f);
            o.z = fmaxf(acc[j].z + b.z, 0.f);
            o.w = fmaxf(acc[j].w + b.w, 0.f);
            *reinterpret_cast<float4*>(hout + (size_t)node * H + og * 4) = o;
        }
    }
}

// ---- K5: CSR fill + both projections, 16KB LDS ----
__global__ __launch_bounds__(256, 8) void fill_and_proj(
        const int* __restrict__ sC, const int* __restrict__ dC,
        const int* __restrict__ sU, const int* __restrict__ dU,
        const int* __restrict__ sA, const int* __restrict__ dA,
        int* __restrict__ nxC, int* __restrict__ nxU, int* __restrict__ nxA,
        int* __restrict__ colC, int* __restrict__ colU, int* __restrict__ colA, int E,
        int fillB,
        const float* __restrict__ xf, const float* __restrict__ wtf,
        const float* __restrict__ bf, float* __restrict__ hf,
        const float* __restrict__ xa, const float* __restrict__ wta,
        const float* __restrict__ ba, float* __restrict__ ha)
{
    __shared__ __align__(16) float4 smem[64 * 16];
    int b = blockIdx.x;
    if (b < fillB) {
        int i = b * 256 + threadIdx.x;
        if (i >= 3 * E) return;
        int rel = i / E, e = i - rel * E;
        if (rel == 0)      { int pos = atomicAdd(&nxC[dC[e]], 1); colC[pos] = sC[e]; }
        else if (rel == 1) { int pos = atomicAdd(&nxU[dU[e]], 1); colU[pos] = sU[e]; }
        else               { int pos = atomicAdd(&nxA[dA[e]], 1); colA[pos] = sA[e]; }
    } else {
        int b2 = b - fillB;
        if (b2 < NBF) proj_body128(xf, wtf, bf, hf, b2 * 64, smem);
        else          proj_body64(xa, wta, ba, ha, (b2 - NBF) * 64, N_API, smem);
    }
}

// ---- 8-deep interleaved CSR gather: 2 edges per node per round ----
__device__ __forceinline__ void gather8(const float* __restrict__ src,
        const int* __restrict__ col, int j[4], const int e[4], int L, float4 a[4])
{
    while (j[0] < e[0] || j[1] < e[1] || j[2] < e[2] || j[3] < e[3]) {
        float4 v[8]; bool act[8];
        #pragma unroll
        for (int p = 0; p < 4; ++p) {
            int jj = j[p];
            act[2 * p]     = jj < e[p];
            act[2 * p + 1] = jj + 1 < e[p];
            if (act[2 * p]) {
                int s = col[jj];
                v[2 * p] = *reinterpret_cast<const float4*>(src + (size_t)s * H + L * 4);
            }
            if (act[2 * p + 1]) {
                int s = col[jj + 1];
                v[2 * p + 1] = *reinterpret_cast<const float4*>(src + (size_t)s * H + L * 4);
            }
            j[p] = jj + 2;
        }
        #pragma unroll
        for (int q = 0; q < 8; ++q) if (act[q]) add4(a[q >> 1], v[q]);
    }
}

// ---- fused layer: register gather + 3 GEMMs; T14 own-row pre-issue; optional fused pool ----
__global__ __launch_bounds__(256, 4) void layer_both(
        const float* __restrict__ hf_old, const float* __restrict__ ha_old,
        float* __restrict__ hf_new, float* __restrict__ ha_new,
        const int* __restrict__ rpC, const int* __restrict__ colC,
        const int* __restrict__ rpU, const int* __restrict__ colU,
        const int* __restrict__ rpA, const int* __restrict__ colA,
        const float* __restrict__ wtr, const float* __restrict__ wtlc,
        const float* __restrict__ wtlu,
        const float* __restrict__ wtruse, const float* __restrict__ wtluse,
        const float* __restrict__ bias_c, const float* __restrict__ bias_u,
        const float* __restrict__ bias_a,
        float* __restrict__ psh)   // nullptr for layer 0; else [NSHADOW][128] shadow sums
{
    __shared__ __align__(16) float4 X[64 * 16];    // 16 KB, reused across phases
    const int b = blockIdx.x;
    const int t = threadIdx.x;
    const int L = t & 15, g = t >> 4;
    const int og = t & 15, ng = t >> 4;
    const float4 z4 = make_float4(0.f, 0.f, 0.f, 0.f);

    float4 acc[4];
    #pragma unroll
    for (int j = 0; j < 4; ++j) acc[j] = z4;
    float4 o4[4];
    #pragma unroll
    for (int j = 0; j < 4; ++j) o4[j] = z4;

    if (b < NBF) {
        const int i0 = b * 64;
        // ---- Phase 1: mean over calls (hf_old) -> GEMM Wlc ----
        {
            int j1[4], e1[4], d1[4]; float4 a1[4];
            #pragma unroll
            for (int p = 0; p < 4; ++p) {
                int node = i0 + p * 16 + g;
                j1[p] = rpC[node]; e1[p] = rpC[node + 1]; d1[p] = e1[p] - j1[p];
                a1[p] = z4;
            }
            gather8(hf_old, colC, j1, e1, L, a1);
            #pragma unroll
            for (int p = 0; p < 4; ++p) {
                int n = p * 16 + g;
                scl4(a1[p], 1.0f / (float)max(d1[p], 1));
                X[n * 16 + (L ^ ((n >> 2) & 7))] = a1[p];
            }
        }
        __syncthreads();
        gemm_acc(X, reinterpret_cast<const float4*>(wtlc), og, ng, acc);
        __syncthreads();
        // ---- Phase 2: mean over usedby (ha_old) -> GEMM Wlu ----
        {
            int j2[4], e2[4], d2[4]; float4 a2[4];
            #pragma unroll
            for (int p = 0; p < 4; ++p) {
                int node = i0 + p * 16 + g;
                j2[p] = rpU[node]; e2[p] = rpU[node + 1]; d2[p] = e2[p] - j2[p];
                a2[p] = z4;
            }
            gather8(ha_old, colU, j2, e2, L, a2);
            #pragma unroll
            for (int p = 0; p < 4; ++p) {
                int n = p * 16 + g;
                scl4(a2[p], 1.0f / (float)max(d2[p], 1));
                X[n * 16 + (L ^ ((n >> 2) & 7))] = a2[p];
            }
        }
        __syncthreads();
        // ---- T14: pre-issue phase-3 own rows; gemm2 hides their latency ----
        float4 ow[4];
        #pragma unroll
        for (int r = 0; r < 4; ++r) {
            int idx = t + r * 256;
            int n = idx >> 4, k4 = idx & 15;
            ow[r] = *reinterpret_cast<const float4*>(hf_old + (size_t)(i0 + n) * H + k4 * 4);
        }
        gemm_acc(X, reinterpret_cast<const float4*>(wtlu), og, ng, acc);
        __syncthreads();
        #pragma unroll
        for (int r = 0; r < 4; ++r) {
            int idx = t + r * 256;
            int n = idx >> 4, k4 = idx & 15;
            X[n * 16 + (k4 ^ ((n >> 2) & 7))] = ow[r];
        }
        __syncthreads();
        gemm_acc(X, reinterpret_cast<const float4*>(wtr), og, ng, acc);
        // ---- epilogue ----
        float4 ba = reinterpret_cast<const float4*>(bias_c)[og];
        float4 bb = reinterpret_cast<const float4*>(bias_u)[og];
        float4 bv = make_float4(ba.x + bb.x, ba.y + bb.y, ba.z + bb.z, ba.w + bb.w);
        #pragma unroll
        for (int j = 0; j < 4; ++j) {
            int node = i0 + ng * 4 + j;
            float4 o;
            o.x = fmaxf(acc[j].x + bv.x, 0.f);
            o.y = fmaxf(acc[j].y + bv.y, 0.f);
            o.z = fmaxf(acc[j].z + bv.z, 0.f);
            o.w = fmaxf(acc[j].w + bv.w, 0.f);
            o4[j] = o;
            *reinterpret_cast<float4*>(hf_new + (size_t)node * H + og * 4) = o;
        }
        if (psh) {
            float4 s = z4;
            #pragma unroll
            for (int j = 0; j < 4; ++j) add4(s, o4[j]);
            __syncthreads();             // X reads done; safe to reuse
            X[ng * 16 + og] = s;
            __syncthreads();
            if (ng == 0) {
                float4 tot = z4;
                #pragma unroll
                for (int q = 0; q < 16; ++q) add4(tot, X[q * 16 + og]);
                float* dst = psh + (size_t)(b & (NSHADOW - 1)) * 128 + og * 4;
                atomicAdd(dst + 0, tot.x); atomicAdd(dst + 1, tot.y);
                atomicAdd(dst + 2, tot.z); atomicAdd(dst + 3, tot.w);
            }
        }
    } else {
        const int i0 = (b - NBF) * 64;
        // ---- Phase 1: mean over uses (hf_old) -> GEMM Wluse ----
        {
            int j1[4], e1[4], d1[4]; float4 a1[4];
            #pragma unroll
            for (int p = 0; p < 4; ++p) {
                int node = i0 + p * 16 + g;
                if (node < N_API) { j1[p] = rpA[node]; e1[p] = rpA[node + 1]; }
                else { j1[p] = 0; e1[p] = 0; }
                d1[p] = e1[p] - j1[p];
                a1[p] = z4;
            }
            gather8(hf_old, colA, j1, e1, L, a1);
            #pragma unroll
            for (int p = 0; p < 4; ++p) {
                int n = p * 16 + g;
                scl4(a1[p], 1.0f / (float)max(d1[p], 1));
                X[n * 16 + (L ^ ((n >> 2) & 7))] = a1[p];
            }
        }
        __syncthreads();
        // ---- T14: pre-issue own rows; gemm1 hides them ----
        float4 ow[4];
        #pragma unroll
        for (int r = 0; r < 4; ++r) {
            int idx = t + r * 256;
            int n = idx >> 4, k4 = idx & 15;
            int node = i0 + n;
            ow[r] = z4;
            if (node < N_API)
                ow[r] = *reinterpret_cast<const float4*>(ha_old + (size_t)node * H + k4 * 4);
        }
        gemm_acc(X, reinterpret_cast<const float4*>(wtluse), og, ng, acc);
        __syncthreads();
        #pragma unroll
        for (int r = 0; r < 4; ++r) {
            int idx = t + r * 256;
            int n = idx >> 4, k4 = idx & 15;
            X[n * 16 + (k4 ^ ((n >> 2) & 7))] = ow[r];
        }
        __syncthreads();
        gemm_acc(X, reinterpret_cast<const float4*>(wtruse), og, ng, acc);
        float4 bv = reinterpret_cast<const float4*>(bias_a)[og];
        #pragma unroll
        for (int j = 0; j < 4; ++j) {
            int node = i0 + ng * 4 + j;
            if (node < N_API) {
                float4 o;
                o.x = fmaxf(acc[j].x + bv.x, 0.f);
                o.y = fmaxf(acc[j].y + bv.y, 0.f);
                o.z = fmaxf(acc[j].z + bv.z, 0.f);
                o.w = fmaxf(acc[j].w + bv.w, 0.f);
                o4[j] = o;
                *reinterpret_cast<float4*>(ha_new + (size_t)node * H + og * 4) = o;
            }
        }
        if (psh) {
            float4 s = z4;
            #pragma unroll
            for (int j = 0; j < 4; ++j) add4(s, o4[j]);
            __syncthreads();
            X[ng * 16 + og] = s;
            __syncthreads();
            if (ng == 0) {
                float4 tot = z4;
                #pragma unroll
                for (int q = 0; q < 16; ++q) add4(tot, X[q * 16 + og]);
                float* dst = psh + (size_t)(b & (NSHADOW - 1)) * 128 + 64 + og * 4;
                atomicAdd(dst + 0, tot.x); atomicAdd(dst + 1, tot.y);
                atomicAdd(dst + 2, tot.z); atomicAdd(dst + 3, tot.w);
            }
        }
    }
}

__global__ __launch_bounds__(128) void classifier_kernel(const float* __restrict__ shadows,
        const float* __restrict__ Wc1, const float* __restrict__ bc1,
        const float* __restrict__ Wc2, const float* __restrict__ bc2,
        float* __restrict__ out)
{
    __shared__ float ps[128];
    __shared__ float z1[64];
    int t = threadIdx.x;
    float s = 0.f;
    for (int q = 0; q < NSHADOW; ++q) s += shadows[q * 128 + t];
    ps[t] = s * (t < 64 ? (1.0f / N_FUNC) : (1.0f / N_API));
    __syncthreads();
    if (t < 64) {
        float a = bc1[t];
        for (int k = 0; k < 128; ++k) a = fmaf(ps[k], Wc1[t * 128 + k], a);
        z1[t] = fmaxf(a, 0.f);
    }
    __syncthreads();
    if (t < 2) {
        float a = bc2[t];
        for (int j = 0; j < 64; ++j) a = fmaf(z1[j], Wc2[t * 64 + j], a);
        out[t] = a;
    }
}

extern "C" void kernel_launch(void* const* d_in, const int* in_sizes, int n_in,
                              void* d_out, int out_size, void* d_ws, size_t ws_size,
                              hipStream_t stream)
{
    const float* x_func    = (const float*)d_in[0];
    const float* x_api     = (const float*)d_in[1];
    const float* w_in_func = (const float*)d_in[2];
    const float* b_in_func = (const float*)d_in[3];
    const float* w_in_api  = (const float*)d_in[4];
    const float* b_in_api  = (const float*)d_in[5];
    const float* Wl_calls  = (const float*)d_in[6];
    const float* bl_calls  = (const float*)d_in[7];
    const float* Wr_calls  = (const float*)d_in[8];
    const float* Wl_uses   = (const float*)d_in[9];
    const float* bl_uses   = (const float*)d_in[10];
    const float* Wr_uses   = (const float*)d_in[11];
    const float* Wl_usedby = (const float*)d_in[12];
    const float* bl_usedby = (const float*)d_in[13];
    const float* Wr_usedby = (const float*)d_in[14];
    const float* Wc1       = (const float*)d_in[15];
    const float* bc1       = (const float*)d_in[16];
    const float* Wc2       = (const float*)d_in[17];
    const float* bc2       = (const float*)d_in[18];
    const int*   ei_calls  = (const int*)d_in[19];
    const int*   ei_uses   = (const int*)d_in[20];
    const int*   ei_usedby = (const int*)d_in[21];
    const int E = in_sizes[19] / 2;

    float* ws = (float*)d_ws;
    size_t off = 0;
    float* hf0 = ws + off; off += (size_t)N_FUNC * H;
    float* hf1 = ws + off; off += (size_t)N_FUNC * H;
    float* ha0 = ws + off; off += (size_t)N_API * H;
    float* ha1 = ws + off; off += (size_t)N_API * H;
    float* prep = ws + off; off += 12288 + 10 * 4096;
    int* cntC = (int*)(ws + off); off += N_FUNC;   // cnt block + shadows contiguous for 1 memset
    int* cntU = (int*)(ws + off); off += N_FUNC;
    int* cntA = (int*)(ws + off); off += N_API;
    float* shadows = ws + off; off += NSHADOW * 128;
    int* rpC = (int*)(ws + off); off += N_FUNC + 1;
    int* rpU = (int*)(ws + off); off += N_FUNC + 1;
    int* rpA = (int*)(ws + off); off += N_API + 1;
    int* nxC = (int*)(ws + off); off += N_FUNC + 1;
    int* nxU = (int*)(ws + off); off += N_FUNC + 1;
    int* nxA = (int*)(ws + off); off += N_API + 1;
    int* colC = (int*)(ws + off); off += E;
    int* colU = (int*)(ws + off); off += E;
    int* colA = (int*)(ws + off); off += E;
    int* partC = (int*)(ws + off); off += 128;
    int* partU = (int*)(ws + off); off += 128;
    int* partA = (int*)(ws + off); off += 128;

    const int nbF = (N_FUNC + SCAN_CHUNK - 1) / SCAN_CHUNK;  // 98
    const int nbA = (N_API + SCAN_CHUNK - 1) / SCAN_CHUNK;   // 25
    const int fillB = (3 * E + 255) / 256;

    hipMemsetAsync(cntC, 0, (size_t)(2 * N_FUNC + N_API + NSHADOW * 128) * sizeof(float), stream);

    prep_and_count<<<PREP_BLOCKS + fillB, 256, 0, stream>>>(
            w_in_func, w_in_api, Wl_calls, Wr_calls, Wl_uses, Wr_uses,
            Wl_usedby, Wr_usedby, prep,
            ei_calls + E, ei_usedby + E, ei_uses + E, cntC, cntU, cntA, E);

    float* wt_in_func = prep;
    float* wt_in_api  = prep + 8192;
    float* wt_r[NLAYERS], *wt_lc[NLAYERS], *wt_lu[NLAYERS], *wt_luse[NLAYERS], *wt_ruse[NLAYERS];
    for (int l = 0; l < NLAYERS; ++l) {
        wt_r[l]    = prep + 12288 + (l * 5 + 0) * 4096;
        wt_lc[l]   = prep + 12288 + (l * 5 + 1) * 4096;
        wt_lu[l]   = prep + 12288 + (l * 5 + 2) * 4096;
        wt_luse[l] = prep + 12288 + (l * 5 + 3) * 4096;
        wt_ruse[l] = prep + 12288 + (l * 5 + 4) * 4096;
    }

    block_sums_all<<<2 * nbF + nbA, 256, 0, stream>>>(
            cntC, cntU, cntA, partC, partU, partA, N_FUNC, N_API, nbF);
    scan_small_all<<<1, 192, 0, stream>>>(partC, partU, partA, nbF, nbA);
    write_rowptr_all<<<2 * nbF + nbA, 256, 0, stream>>>(
            cntC, cntU, cntA, partC, partU, partA,
            rpC, rpU, rpA, nxC, nxU, nxA, N_FUNC, N_API, nbF, E);
    fill_and_proj<<<fillB + NBF + NBA, 256, 0, stream>>>(
            ei_calls, ei_calls + E, ei_usedby, ei_usedby + E, ei_uses, ei_uses + E,
            nxC, nxU, nxA, colC, colU, colA, E, fillB,
            x_func, wt_in_func, b_in_func, hf0,
            x_api, wt_in_api, b_in_api, ha0);

    float* hf[2] = { hf0, hf1 };
    float* ha[2] = { ha0, ha1 };
    for (int l = 0; l < NLAYERS; ++l) {
        int cur = l & 1, nxt = cur ^ 1;
        layer_both<<<NBF + NBA, 256, 0, stream>>>(
                hf[cur], ha[cur], hf[nxt], ha[nxt],
                rpC, colC, rpU, colU, rpA, colA,
                wt_r[l], wt_lc[l], wt_lu[l], wt_ruse[l], wt_luse[l],
                bl_calls + l * 64, bl_usedby + l * 64, bl_uses + l * 64,
                (l == NLAYERS - 1) ? shadows : nullptr);
    }

    classifier_kernel<<<1, 128, 0, stream>>>(shadows, Wc1, bc1, Wc2, bc2, (float*)d_out);
}